// Round 4
// baseline (280.099 us; speedup 1.0000x reference)
//
#include <hip/hip_runtime.h>

typedef unsigned short u16;
typedef unsigned int   u32;

#define NB     20000   // batch of target nodes
#define SNB    25      // sampled neighbors (padded)
#define FEAT   256
#define K2     512     // 2*FEAT (concat dim)
#define OUTF   256

// d_ws layout (bytes):
//   [0]                 int flag: 1 = tensors are bf16, 0 = float32
//   [64]                combined bf16 [20000][512]  = 20,480,000 B
//   [64 + 20,480,000]   w1 as bf16   [256][512]     =    262,144 B
#define WS_COMB_OFF 64
#define WS_W1_OFF   (64 + NB * K2 * 2)

__device__ __forceinline__ float bf2f(u32 lo16) {
  union { u32 i; float f; } x; x.i = lo16 << 16; return x.f;
}
__device__ __forceinline__ u32 f2bf(float f) {
  union { u32 i; float f; } x; x.f = f;
  return (x.i + 0x7fffu + ((x.i >> 16) & 1u)) >> 16;  // RNE; identity on bf16
}

// ---------------------------------------------------------------------------
// Probe: decide whether float tensors are bf16-packed or raw float32.
// For bf16 pairs the low u16 is a bf16 of a ~N(0,1) sample -> exponent field
// in [100,150] essentially always. For f32, low u16 = mantissa garbage ->
// exponent field uniform (~20% hit rate). Vote over 256 words, threshold 128.
// ---------------------------------------------------------------------------
__global__ void probe_kernel(const u32* __restrict__ feats_raw,
                             int* __restrict__ flag) {
  const int t = threadIdx.x;  // one wave, 0..63
  int hits = 0;
#pragma unroll
  for (int i = 0; i < 4; ++i) {
    const u32 w = feats_raw[t * 4 + i];
    const u32 lo = w & 0xffffu;
    const u32 e = (lo >> 7) & 0xffu;
    if ((e >= 100u && e <= 150u) || lo == 0u) ++hits;
  }
  for (int off = 32; off > 0; off >>= 1) hits += __shfl_down(hits, off);
  if (t == 0) *flag = (hits >= 128) ? 1 : 0;
}

// ---------------------------------------------------------------------------
// Convert w1 to bf16 (identity copy if already bf16).
// ---------------------------------------------------------------------------
__global__ __launch_bounds__(256) void convw_kernel(
    const void* __restrict__ w_raw, u16* __restrict__ w_bf,
    const int* __restrict__ flag) {
  const int i = blockIdx.x * 256 + threadIdx.x;  // 0..131071
  if (*flag) w_bf[i] = ((const u16*)w_raw)[i];
  else       w_bf[i] = (u16)f2bf(((const float*)w_raw)[i]);
}

// ---------------------------------------------------------------------------
// Aggregation: combined[b,0:256] = feats[nodes[b]];
//              combined[b,256:512] = mean(feats[samp_neighs[b,:len]]).
// One block per node, 128 threads; thread t handles elements 2t, 2t+1.
// ---------------------------------------------------------------------------
__global__ __launch_bounds__(128) void agg_kernel(
    const void* __restrict__ feats_raw, const int* __restrict__ nodes,
    const int* __restrict__ neighs, const int* __restrict__ lens,
    u16* __restrict__ combined, const int* __restrict__ flag) {
  const int b = blockIdx.x;
  const int t = threadIdx.x;  // 0..127
  const int isbf = *flag;     // uniform branch

  __shared__ int sidx[SNB];
  if (t < SNB) sidx[t] = neighs[b * SNB + t];
  const int self = nodes[b];
  const int len  = lens[b];   // guaranteed >= 1
  __syncthreads();

  float e0, e1, s0 = 0.f, s1 = 0.f;
  if (isbf) {
    const u16* feats = (const u16*)feats_raw;
    const u32 sv = ((const u32*)(feats + (size_t)self * FEAT))[t];
    e0 = bf2f(sv & 0xffffu); e1 = bf2f(sv >> 16);
    for (int s = 0; s < len; ++s) {
      const u32 v = ((const u32*)(feats + (size_t)sidx[s] * FEAT))[t];
      s0 += bf2f(v & 0xffffu); s1 += bf2f(v >> 16);
    }
  } else {
    const float* feats = (const float*)feats_raw;
    const float2 sv = ((const float2*)(feats + (size_t)self * FEAT))[t];
    e0 = sv.x; e1 = sv.y;
    for (int s = 0; s < len; ++s) {
      const float2 v = ((const float2*)(feats + (size_t)sidx[s] * FEAT))[t];
      s0 += v.x; s1 += v.y;
    }
  }
  const float inv = 1.f / (float)len;
  u32* crow = (u32*)(combined + (size_t)b * K2);
  crow[t]       = f2bf(e0) | (f2bf(e1) << 16);
  crow[128 + t] = f2bf(s0 * inv) | (f2bf(s1 * inv) << 16);
}

// ---------------------------------------------------------------------------
// GEMM: out[M,256] = relu(combined[M,512] @ w1[256,512]^T).
// Pure-VALU fp32 (verified structure from round 3). 64x64 tile, 256 threads,
// 4x4 outputs/thread, K-tiles of 16, padded LDS (conflict-free).
// ---------------------------------------------------------------------------
#define TM 64
#define TN 64
#define TK 16

__global__ __launch_bounds__(256) void gemm_kernel(
    const u16* __restrict__ A,   // [M, 512] combined bf16 (K-contiguous)
    const u16* __restrict__ W,   // [256, 512] w1 bf16 (K-contiguous)
    void* __restrict__ Cout,     // [M, 256] bf16 or f32 per flag
    int M, const int* __restrict__ flag) {
  __shared__ float As[TM][TK + 1];
  __shared__ float Ws[TN][TK + 1];

  const int tid = threadIdx.x;
  const int tx  = tid & 15;
  const int ty  = tid >> 4;
  const int m0  = blockIdx.x * TM;
  const int n0  = blockIdx.y * TN;

  float acc[4][4] = {{0.f}};

  const int srow = tid >> 2;         // staging row 0..63
  const int sc4  = (tid & 3) * 4;    // staging col 0,4,8,12

  int am = m0 + srow; if (am >= M) am = M - 1;  // clamp; results predicated
  const u16* pa_base = A + (size_t)am * K2 + sc4;
  const u16* pw_base = W + (size_t)(n0 + srow) * K2 + sc4;

  for (int k0 = 0; k0 < K2; k0 += TK) {
    const u32 a01 = *(const u32*)(pa_base + k0);
    const u32 a23 = *(const u32*)(pa_base + k0 + 2);
    As[srow][sc4 + 0] = bf2f(a01 & 0xffffu);
    As[srow][sc4 + 1] = bf2f(a01 >> 16);
    As[srow][sc4 + 2] = bf2f(a23 & 0xffffu);
    As[srow][sc4 + 3] = bf2f(a23 >> 16);
    const u32 w01 = *(const u32*)(pw_base + k0);
    const u32 w23 = *(const u32*)(pw_base + k0 + 2);
    Ws[srow][sc4 + 0] = bf2f(w01 & 0xffffu);
    Ws[srow][sc4 + 1] = bf2f(w01 >> 16);
    Ws[srow][sc4 + 2] = bf2f(w23 & 0xffffu);
    Ws[srow][sc4 + 3] = bf2f(w23 >> 16);
    __syncthreads();

#pragma unroll
    for (int k = 0; k < TK; ++k) {
      float a[4], w[4];
#pragma unroll
      for (int i = 0; i < 4; ++i) a[i] = As[ty + 16 * i][k];
#pragma unroll
      for (int j = 0; j < 4; ++j) w[j] = Ws[tx + 16 * j][k];
#pragma unroll
      for (int i = 0; i < 4; ++i)
#pragma unroll
        for (int j = 0; j < 4; ++j) acc[i][j] += a[i] * w[j];
    }
    __syncthreads();
  }

  const int isbf = *flag;
#pragma unroll
  for (int i = 0; i < 4; ++i) {
    const int row = m0 + ty + 16 * i;
    if (row < M) {
#pragma unroll
      for (int j = 0; j < 4; ++j) {
        const int col = n0 + tx + 16 * j;
        float v = acc[i][j];
        v = v > 0.f ? v : 0.f;
        if (isbf) ((u16*)Cout)[(size_t)row * OUTF + col] = (u16)f2bf(v);
        else      ((float*)Cout)[(size_t)row * OUTF + col] = v;
      }
    }
  }
}

// ---------------------------------------------------------------------------
extern "C" void kernel_launch(void* const* d_in, const int* in_sizes, int n_in,
                              void* d_out, int out_size, void* d_ws, size_t ws_size,
                              hipStream_t stream) {
  const void* feats = d_in[0];               // [100000, 256] bf16 OR f32
  const int* nodes  = (const int*)d_in[1];   // [20000]
  const int* neighs = (const int*)d_in[2];   // [20000, 25]
  const int* lens   = (const int*)d_in[3];   // [20000]
  // d_in[4] = w0 — dead: layer-0 output is discarded by the reference loop
  // (combined is rebuilt from unchanged self_raw/agg before w1 is applied).
  const void* w1    = d_in[5];               // [256, 512] bf16 OR f32

  char* ws = (char*)d_ws;
  int* flag     = (int*)ws;
  u16* combined = (u16*)(ws + WS_COMB_OFF);  // [20000, 512] bf16
  u16* w1bf     = (u16*)(ws + WS_W1_OFF);    // [256, 512] bf16

  probe_kernel<<<1, 64, 0, stream>>>((const u32*)feats, flag);
  convw_kernel<<<512, 256, 0, stream>>>(w1, w1bf, flag);
  agg_kernel<<<NB, 128, 0, stream>>>(feats, nodes, neighs, lens, combined, flag);

  dim3 grid((NB + TM - 1) / TM, OUTF / TN);  // 313 x 4
  gemm_kernel<<<grid, 256, 0, stream>>>(combined, w1bf, d_out, NB, flag);
}

// Round 5
// 205.979 us; speedup vs baseline: 1.3598x; 1.3598x over previous
//
#include <hip/hip_runtime.h>

typedef unsigned short u16;
typedef unsigned int   u32;

#define NB     20000   // batch of target nodes
#define SNB    25      // sampled neighbors (padded)
#define FEAT   256
#define K2     512     // 2*FEAT (concat dim)
#define OUTF   256

// d_ws layout (bytes):
//   [0]                 int flag: 1 = tensors are bf16, 0 = float32
//   [64]                combined bf16 [20000][512]  = 20,480,000 B
//   [64 + 20,480,000]   w1 as bf16   [256][512]     =    262,144 B
#define WS_COMB_OFF 64
#define WS_W1_OFF   (64 + NB * K2 * 2)

__device__ __forceinline__ float bf2f(u32 lo16) {
  union { u32 i; float f; } x; x.i = lo16 << 16; return x.f;
}
__device__ __forceinline__ u32 f2bf(float f) {
  union { u32 i; float f; } x; x.f = f;
  return (x.i + 0x7fffu + ((x.i >> 16) & 1u)) >> 16;  // RNE; identity on bf16
}
__device__ __forceinline__ u32 pack2(float a, float b) {
  return f2bf(a) | (f2bf(b) << 16);
}

// ---------------------------------------------------------------------------
// Probe: decide whether float tensors are bf16-packed or raw float32.
// (unchanged from the passing round-4 kernel)
// ---------------------------------------------------------------------------
__global__ void probe_kernel(const u32* __restrict__ feats_raw,
                             int* __restrict__ flag) {
  const int t = threadIdx.x;  // one wave, 0..63
  int hits = 0;
#pragma unroll
  for (int i = 0; i < 4; ++i) {
    const u32 w = feats_raw[t * 4 + i];
    const u32 lo = w & 0xffffu;
    const u32 e = (lo >> 7) & 0xffu;
    if ((e >= 100u && e <= 150u) || lo == 0u) ++hits;
  }
  for (int off = 32; off > 0; off >>= 1) hits += __shfl_down(hits, off);
  if (t == 0) *flag = (hits >= 128) ? 1 : 0;
}

// ---------------------------------------------------------------------------
// Convert w1 to bf16 (identity copy if already bf16).
// ---------------------------------------------------------------------------
__global__ __launch_bounds__(256) void convw_kernel(
    const void* __restrict__ w_raw, u16* __restrict__ w_bf,
    const int* __restrict__ flag) {
  const int i = blockIdx.x * 256 + threadIdx.x;  // 0..131071
  if (*flag) w_bf[i] = ((const u16*)w_raw)[i];
  else       w_bf[i] = (u16)f2bf(((const float*)w_raw)[i]);
}

// ---------------------------------------------------------------------------
// Aggregation: combined[b,0:256] = feats[nodes[b]];
//              combined[b,256:512] = mean(feats[samp_neighs[b,:len]]).
// One WAVE per node (4 nodes / 256-thread block). Lane handles 4 elements:
// 8-B loads (bf16) / 16-B loads (f32). Neighbor ids broadcast via shfl.
// ---------------------------------------------------------------------------
__global__ __launch_bounds__(256) void agg_kernel(
    const void* __restrict__ feats_raw, const int* __restrict__ nodes,
    const int* __restrict__ neighs, const int* __restrict__ lens,
    u16* __restrict__ combined, const int* __restrict__ flag) {
  const int b    = blockIdx.x * 4 + (threadIdx.x >> 6);  // node id
  const int lane = threadIdx.x & 63;
  const int isbf = *flag;     // uniform branch

  const int self = nodes[b];
  const int len  = lens[b];   // guaranteed >= 1
  int myidx = (lane < SNB) ? neighs[b * SNB + lane] : 0;

  float e0, e1, e2, e3;                       // self, elements 4l..4l+3
  float s0 = 0.f, s1 = 0.f, s2 = 0.f, s3 = 0.f;  // neighbor sums
  if (isbf) {
    const u16* feats = (const u16*)feats_raw;
    const uint2 sv = ((const uint2*)(feats + (size_t)self * FEAT))[lane];
    e0 = bf2f(sv.x & 0xffffu); e1 = bf2f(sv.x >> 16);
    e2 = bf2f(sv.y & 0xffffu); e3 = bf2f(sv.y >> 16);
    for (int s = 0; s < len; ++s) {
      const int idx = __shfl(myidx, s);
      const uint2 v = ((const uint2*)(feats + (size_t)idx * FEAT))[lane];
      s0 += bf2f(v.x & 0xffffu); s1 += bf2f(v.x >> 16);
      s2 += bf2f(v.y & 0xffffu); s3 += bf2f(v.y >> 16);
    }
  } else {
    const float* feats = (const float*)feats_raw;
    const float4 sv = ((const float4*)(feats + (size_t)self * FEAT))[lane];
    e0 = sv.x; e1 = sv.y; e2 = sv.z; e3 = sv.w;
    for (int s = 0; s < len; ++s) {
      const int idx = __shfl(myidx, s);
      const float4 v = ((const float4*)(feats + (size_t)idx * FEAT))[lane];
      s0 += v.x; s1 += v.y; s2 += v.z; s3 += v.w;
    }
  }
  const float inv = 1.f / (float)len;
  uint2* crow = (uint2*)(combined + (size_t)b * K2);
  uint2 pe; pe.x = pack2(e0, e1); pe.y = pack2(e2, e3);
  crow[lane] = pe;
  uint2 pm; pm.x = pack2(s0 * inv, s1 * inv); pm.y = pack2(s2 * inv, s3 * inv);
  crow[64 + lane] = pm;
}

// ---------------------------------------------------------------------------
// GEMM: out[M,256] = relu(combined[M,512] @ w1[256,512]^T), fp32 MFMA acc.
// 128x128 block tile, BK=32, 4 waves in 2x2, each wave 64x64 = 4x4 MFMA
// 16x16x32 bf16. Plain uint4->LDS staging, +8-elem row pad (2-way bank
// aliasing only -> free per m136). Fragments typed as short8 per the
// compile-verified gfx950 example (NOT __bf16 vectors).
// ---------------------------------------------------------------------------
typedef __attribute__((ext_vector_type(8))) short short8;
typedef __attribute__((ext_vector_type(4))) float f32x4;

#define BM 128
#define BN 128
#define BK 32
#define LDST 40   // 32 + 8 pad elements

__global__ __launch_bounds__(256) void gemm_kernel(
    const u16* __restrict__ A,   // [M, 512] combined bf16 (K-contiguous)
    const u16* __restrict__ W,   // [256, 512] w1 bf16 (K-contiguous)
    void* __restrict__ Cout,     // [M, 256] bf16 or f32 per flag
    int M, const int* __restrict__ flag) {
  __shared__ u16 As[BM * LDST];
  __shared__ u16 Bs[BN * LDST];

  const int tid  = threadIdx.x;
  const int wave = tid >> 6;
  const int lane = tid & 63;
  const int m0 = blockIdx.x * BM;
  const int n0 = blockIdx.y * BN;

  const int wr = (wave >> 1) * 64;  // wave sub-tile row origin
  const int wc = (wave & 1) * 64;   // wave sub-tile col origin

  f32x4 acc[4][4] = {};

  const int r16 = lane & 15;
  const int kq  = (lane >> 4) * 8;   // k-offset of this lane's quad

  const int srow = tid >> 2;         // staging row 0..63 (+64 on 2nd chunk)
  const int skc  = tid & 3;          // 16-B chunk within the 32-elem k-slice

  for (int k0 = 0; k0 < K2; k0 += BK) {
#pragma unroll
    for (int i = 0; i < 2; ++i) {
      const int row = i * 64 + srow;
      int ar = m0 + row; if (ar >= M) ar = M - 1;   // clamp; results predicated
      const uint4 va = ((const uint4*)(A + (size_t)ar * K2 + k0))[skc];
      *(uint4*)&As[row * LDST + skc * 8] = va;
      const uint4 vb = ((const uint4*)(W + (size_t)(n0 + row) * K2 + k0))[skc];
      *(uint4*)&Bs[row * LDST + skc * 8] = vb;
    }
    __syncthreads();

    short8 af[4], bf[4];
#pragma unroll
    for (int i = 0; i < 4; ++i)
      af[i] = *(const short8*)&As[(wr + i * 16 + r16) * LDST + kq];
#pragma unroll
    for (int j = 0; j < 4; ++j)
      bf[j] = *(const short8*)&Bs[(wc + j * 16 + r16) * LDST + kq];

#pragma unroll
    for (int i = 0; i < 4; ++i)
#pragma unroll
      for (int j = 0; j < 4; ++j)
        acc[i][j] = __builtin_amdgcn_mfma_f32_16x16x32_bf16(af[i], bf[j],
                                                            acc[i][j], 0, 0, 0);
    __syncthreads();
  }

  // Epilogue: C/D layout col = lane&15, row = (lane>>4)*4 + reg  [m89]
  const int isbf = *flag;
#pragma unroll
  for (int i = 0; i < 4; ++i) {
#pragma unroll
    for (int r = 0; r < 4; ++r) {
      const int row = m0 + wr + i * 16 + (lane >> 4) * 4 + r;
      if (row < M) {
#pragma unroll
        for (int j = 0; j < 4; ++j) {
          const int col = n0 + wc + j * 16 + (lane & 15);
          float v = acc[i][j][r];
          v = v > 0.f ? v : 0.f;
          if (isbf) ((u16*)Cout)[(size_t)row * OUTF + col] = (u16)f2bf(v);
          else      ((float*)Cout)[(size_t)row * OUTF + col] = v;
        }
      }
    }
  }
}

// ---------------------------------------------------------------------------
extern "C" void kernel_launch(void* const* d_in, const int* in_sizes, int n_in,
                              void* d_out, int out_size, void* d_ws, size_t ws_size,
                              hipStream_t stream) {
  const void* feats = d_in[0];               // [100000, 256] bf16 OR f32
  const int* nodes  = (const int*)d_in[1];   // [20000]
  const int* neighs = (const int*)d_in[2];   // [20000, 25]
  const int* lens   = (const int*)d_in[3];   // [20000]
  // d_in[4] = w0 — dead: layer-0 output is discarded by the reference loop
  // (combined is rebuilt from unchanged self_raw/agg before w1 is applied).
  const void* w1    = d_in[5];               // [256, 512] bf16 OR f32

  char* ws = (char*)d_ws;
  int* flag     = (int*)ws;
  u16* combined = (u16*)(ws + WS_COMB_OFF);  // [20000, 512] bf16
  u16* w1bf     = (u16*)(ws + WS_W1_OFF);    // [256, 512] bf16

  probe_kernel<<<1, 64, 0, stream>>>((const u32*)feats, flag);
  convw_kernel<<<512, 256, 0, stream>>>(w1, w1bf, flag);
  agg_kernel<<<NB / 4, 256, 0, stream>>>(feats, nodes, neighs, lens, combined, flag);

  dim3 grid((NB + BM - 1) / BM, OUTF / BN);  // 157 x 2
  gemm_kernel<<<grid, 256, 0, stream>>>(combined, w1bf, d_out, NB, flag);
}

// Round 8
// 199.344 us; speedup vs baseline: 1.4051x; 1.0333x over previous
//
#include <hip/hip_runtime.h>

typedef unsigned short u16;
typedef unsigned int   u32;

#define NB     20000   // batch of target nodes
#define SNB    25      // sampled neighbors (padded)
#define FEAT   256
#define K2     512     // 2*FEAT (concat dim)
#define OUTF   256

// DTYPE (settled by execution evidence, rounds 2-7):
//   feats/w0/w1/out are FLOAT32. bf16-interp kernel -> inf; probe kernel chose
//   f32 path and passed; agg FETCH 137 MB matches 100 MB f32 table; bf16-
//   written output failed with untouched-zeros signature.
// d_ws layout (bytes):
//   [0]           combined bf16 [20000][512] = 20,480,000 B  (MFMA A operand)
//   [20,480,000]  w1 as bf16    [256][512]   =    262,144 B  (MFMA B operand)
#define WS_W1_OFF (NB * K2 * 2)

__device__ __forceinline__ u32 f2bf(float f) {
  union { u32 i; float f; } x; x.f = f;
  return (x.i + 0x7fffu + ((x.i >> 16) & 1u)) >> 16;  // RNE
}
__device__ __forceinline__ u32 pack2(float a, float b) {
  return f2bf(a) | (f2bf(b) << 16);
}

// ---------------------------------------------------------------------------
// w1 f32 -> bf16 (131072 elements).
// ---------------------------------------------------------------------------
__global__ __launch_bounds__(256) void convw_kernel(
    const float* __restrict__ w_raw, u16* __restrict__ w_bf) {
  const int i = blockIdx.x * 256 + threadIdx.x;
  w_bf[i] = (u16)f2bf(w_raw[i]);
}

// ---------------------------------------------------------------------------
// Aggregation: combined[b,0:256] = feats[nodes[b]] (bf16-rounded);
//              combined[b,256:512] = mean(feats[samp_neighs[b,:len]]).
// One wave per node (4 waves/block); lane covers 4 floats (16 B) of the row.
// Neighbor loop unrolled x4 with independent float4 accumulators -> 4 gathers
// in flight per wave (round-5: rolled loop latency-bound, 2.65 TB/s, VALU 10%).
// ---------------------------------------------------------------------------
__global__ __launch_bounds__(256) void agg_kernel(
    const float* __restrict__ feats, const int* __restrict__ nodes,
    const int* __restrict__ neighs, const int* __restrict__ lens,
    u16* __restrict__ combined) {
  const int b    = blockIdx.x * 4 + (threadIdx.x >> 6);  // node id
  const int lane = threadIdx.x & 63;

  const int self = nodes[b];
  const int len  = lens[b];   // guaranteed >= 1
  int myidx = (lane < SNB) ? neighs[b * SNB + lane] : 0;

  const float4 sv = ((const float4*)(feats + (size_t)self * FEAT))[lane];

  float4 a0 = {0.f, 0.f, 0.f, 0.f}, a1 = a0, a2 = a0, a3 = a0;
  int s = 0;
  for (; s + 4 <= len; s += 4) {
    const int i0 = __shfl(myidx, s);
    const int i1 = __shfl(myidx, s + 1);
    const int i2 = __shfl(myidx, s + 2);
    const int i3 = __shfl(myidx, s + 3);
    const float4 v0 = ((const float4*)(feats + (size_t)i0 * FEAT))[lane];
    const float4 v1 = ((const float4*)(feats + (size_t)i1 * FEAT))[lane];
    const float4 v2 = ((const float4*)(feats + (size_t)i2 * FEAT))[lane];
    const float4 v3 = ((const float4*)(feats + (size_t)i3 * FEAT))[lane];
    a0.x += v0.x; a0.y += v0.y; a0.z += v0.z; a0.w += v0.w;
    a1.x += v1.x; a1.y += v1.y; a1.z += v1.z; a1.w += v1.w;
    a2.x += v2.x; a2.y += v2.y; a2.z += v2.z; a2.w += v2.w;
    a3.x += v3.x; a3.y += v3.y; a3.z += v3.z; a3.w += v3.w;
  }
  for (; s < len; ++s) {
    const int i0 = __shfl(myidx, s);
    const float4 v0 = ((const float4*)(feats + (size_t)i0 * FEAT))[lane];
    a0.x += v0.x; a0.y += v0.y; a0.z += v0.z; a0.w += v0.w;
  }
  const float inv = 1.f / (float)len;
  const float m0 = (a0.x + a1.x + a2.x + a3.x) * inv;
  const float m1 = (a0.y + a1.y + a2.y + a3.y) * inv;
  const float m2 = (a0.z + a1.z + a2.z + a3.z) * inv;
  const float m3 = (a0.w + a1.w + a2.w + a3.w) * inv;

  uint2* crow = (uint2*)(combined + (size_t)b * K2);
  uint2 pe; pe.x = pack2(sv.x, sv.y); pe.y = pack2(sv.z, sv.w);
  crow[lane] = pe;
  uint2 pm; pm.x = pack2(m0, m1); pm.y = pack2(m2, m3);
  crow[64 + lane] = pm;
}

// ---------------------------------------------------------------------------
// GEMM: out[M,256] = relu(combined[M,512] @ w1bf[256,512]^T), f32 out.
// KNOWN-GOOD build (ran in round-5's 206 us pass): 128x128 tile, BK=32,
// 4 waves 2x2, wave 64x64 = 4x4 MFMA 16x16x32 bf16 (short8 fragments),
// uint4->LDS staging with +8 row pad. Only change: f32 output stores.
// ---------------------------------------------------------------------------
typedef __attribute__((ext_vector_type(8))) short short8;
typedef __attribute__((ext_vector_type(4))) float f32x4;

#define BM 128
#define BN 128
#define BK 32
#define LDST 40   // 32 + 8 pad elements

__global__ __launch_bounds__(256) void gemm_kernel(
    const u16* __restrict__ A,   // [M, 512] combined bf16 (K-contiguous)
    const u16* __restrict__ W,   // [256, 512] w1 bf16 (K-contiguous)
    float* __restrict__ C,       // [M, 256] f32
    int M) {
  __shared__ u16 As[BM * LDST];
  __shared__ u16 Bs[BN * LDST];

  const int tid  = threadIdx.x;
  const int wave = tid >> 6;
  const int lane = tid & 63;
  const int m0 = blockIdx.x * BM;
  const int n0 = blockIdx.y * BN;

  const int wr = (wave >> 1) * 64;  // wave sub-tile row origin
  const int wc = (wave & 1) * 64;   // wave sub-tile col origin

  f32x4 acc[4][4] = {};

  const int r16 = lane & 15;
  const int kq  = (lane >> 4) * 8;   // k-offset of this lane's quad

  const int srow = tid >> 2;         // staging row 0..63 (+64 on 2nd chunk)
  const int skc  = tid & 3;          // 16-B chunk within 32-elem k-slice

  for (int k0 = 0; k0 < K2; k0 += BK) {
#pragma unroll
    for (int i = 0; i < 2; ++i) {
      const int row = i * 64 + srow;
      int ar = m0 + row; if (ar >= M) ar = M - 1;   // clamp; results predicated
      const uint4 va = ((const uint4*)(A + (size_t)ar * K2 + k0))[skc];
      *(uint4*)&As[row * LDST + skc * 8] = va;
      const uint4 vb = ((const uint4*)(W + (size_t)(n0 + row) * K2 + k0))[skc];
      *(uint4*)&Bs[row * LDST + skc * 8] = vb;
    }
    __syncthreads();

    short8 af[4], bf[4];
#pragma unroll
    for (int i = 0; i < 4; ++i)
      af[i] = *(const short8*)&As[(wr + i * 16 + r16) * LDST + kq];
#pragma unroll
    for (int j = 0; j < 4; ++j)
      bf[j] = *(const short8*)&Bs[(wc + j * 16 + r16) * LDST + kq];

#pragma unroll
    for (int i = 0; i < 4; ++i)
#pragma unroll
      for (int j = 0; j < 4; ++j)
        acc[i][j] = __builtin_amdgcn_mfma_f32_16x16x32_bf16(af[i], bf[j],
                                                            acc[i][j], 0, 0, 0);
    __syncthreads();
  }

  // Epilogue: C/D layout col = lane&15, row = (lane>>4)*4 + reg  [m89]
#pragma unroll
  for (int i = 0; i < 4; ++i) {
#pragma unroll
    for (int r = 0; r < 4; ++r) {
      const int row = m0 + wr + i * 16 + (lane >> 4) * 4 + r;
      if (row < M) {
#pragma unroll
        for (int j = 0; j < 4; ++j) {
          const int col = n0 + wc + j * 16 + (lane & 15);
          float v = acc[i][j][r];
          C[(size_t)row * OUTF + col] = v > 0.f ? v : 0.f;
        }
      }
    }
  }
}

// ---------------------------------------------------------------------------
extern "C" void kernel_launch(void* const* d_in, const int* in_sizes, int n_in,
                              void* d_out, int out_size, void* d_ws, size_t ws_size,
                              hipStream_t stream) {
  const float* feats = (const float*)d_in[0];  // [100000, 256] f32
  const int* nodes   = (const int*)d_in[1];    // [20000]
  const int* neighs  = (const int*)d_in[2];    // [20000, 25]
  const int* lens    = (const int*)d_in[3];    // [20000]
  // d_in[4] = w0 — dead: layer-0 output is discarded by the reference loop.
  const float* w1    = (const float*)d_in[5];  // [256, 512] f32
  float* out = (float*)d_out;                  // [20000, 256] f32

  char* ws = (char*)d_ws;
  u16* combined = (u16*)ws;                    // [20000, 512] bf16
  u16* w1bf     = (u16*)(ws + WS_W1_OFF);      // [256, 512] bf16

  convw_kernel<<<512, 256, 0, stream>>>(w1, w1bf);
  agg_kernel<<<NB / 4, 256, 0, stream>>>(feats, nodes, neighs, lens, combined);

  dim3 grid((NB + BM - 1) / BM, OUTF / BN);    // 157 x 2
  gemm_kernel<<<grid, 256, 0, stream>>>(combined, w1bf, out, NB);
}